// Round 1
// 1009.941 us; speedup vs baseline: 1.0396x; 1.0396x over previous
//
#include <hip/hip_runtime.h>

typedef unsigned short u16;
typedef _Float16 f16;
typedef _Float16 f16x8 __attribute__((ext_vector_type(8)));
typedef _Float16 f16x2 __attribute__((ext_vector_type(2)));
typedef float f32x4 __attribute__((ext_vector_type(4)));

#define AS1 __attribute__((address_space(1)))
#define AS3 __attribute__((address_space(3)))

constexpr int N_NODES = 8000;
constexpr int N_EDGES = 64000;
constexpr int F_IN    = 2560;   // in channels (== H*C, both layers)
constexpr int HEADS   = 8;
constexpr int CPH     = 320;    // channels per head
constexpr int HC      = 2560;   // HEADS*CPH
constexpr int NW      = 5120;   // fused GEMM output width (XL | XR)
constexpr int NGRAPH  = 16;
constexpr float SLOPE = 0.2f;

// ---------------- f32 -> f16 bulk convert (n divisible by 1024) ----------------
__global__ __launch_bounds__(256)
void cvt_f32_f16(const float* __restrict__ in, f16* __restrict__ out, int n)
{
  const int i = (blockIdx.x * 256 + threadIdx.x) * 4;
  if (i >= n) return;
  const float4 v = *(const float4*)(in + i);
  f16 o[4] = {(f16)v.x, (f16)v.y, (f16)v.z, (f16)v.w};
  *(ushort4*)(out + i) = *(const ushort4*)o;
}

// ------ weight transpose + convert: in f32 [R=2560][C=2560] -> out f16 [C][R] ------
__global__ __launch_bounds__(256)
void transpose_w(const float* __restrict__ in, f16* __restrict__ out)
{
  __shared__ u16 tile[64][66];     // +2 pad to break bank stride
  const int bx = blockIdx.x * 64;  // col tile (input)
  const int by = blockIdx.y * 64;  // row tile (input)
  const int tx = threadIdx.x & 63;
  const int ty = threadIdx.x >> 6;
  #pragma unroll
  for (int i = ty; i < 64; i += 4) {
    f16 h = (f16)in[(size_t)(by + i) * HC + bx + tx];
    u16 u; __builtin_memcpy(&u, &h, 2);
    tile[i][tx] = u;
  }
  __syncthreads();
  #pragma unroll
  for (int i = ty; i < 64; i += 4) {
    u16 u = tile[tx][i];
    f16 h; __builtin_memcpy(&h, &u, 2);
    out[(size_t)(bx + i) * F_IN + by + tx] = h;
  }
}

// ---- Fused GEMM: [XL|XR][M,5120](f16) = A[M,K](f16) @ BT[5120,K]^T + bias; fp32 acc ----
// 8-phase pipelined 256x256 tile, BK=64, 512 threads / 8 waves (2M x 4N),
// per-wave 128x64 output (8x4 16x16x32 fragments). 128 KiB LDS double buffer.
// Counted vmcnt(4) at phases 4/8 only; raw s_barrier (no vmcnt drain); setprio
// around MFMA clusters. Per-row XOR-8 16B-chunk swizzle -> 2-way (free) on
// ds_read_b128 and matching pre-swizzled global source for global_load_lds.
//
// Stage schedule (iteration computes K-tiles T=2i from buf0 in ph1-4, T+1 from
// buf1 in ph5-8); every stage target is provably dead since an earlier barrier:
//   ph1: A0(T+1)->sA1   ph2: A1(T+1)->sA1   (sA1 dead since prev ph8)
//   ph3: B0(T+2)->sB0   ph4: B1(T+2)->sB0   (sB0 dead after ph1)
//   ph5: A0(T+2)->sA0   ph6: A1(T+2)->sA0   (sA0 dead after ph4)
//   ph7: B0(T+3)->sB1   ph8: B1(T+3)->sB1   (sB1 dead after ph5)
// vmcnt(4) @ph4: lands A(T+1)[ph1-2] + B(T+1)[prev ph7-8] before ph5 reads.
// vmcnt(4) @ph8: lands B(T+2)[ph3-4] + A(T+2)[ph5-6] before next ph1 reads.
__global__ __launch_bounds__(512, 2)
void gemm_fused(const f16* __restrict__ A, const f16* __restrict__ BT,
                const float* __restrict__ bl, const float* __restrict__ br,
                f16* __restrict__ XL, f16* __restrict__ XR)
{
  __shared__ __align__(16) f16 sm[65536];   // 128 KiB
  f16* const sA0 = sm;
  f16* const sA1 = sm + 16384;
  f16* const sB0 = sm + 32768;
  f16* const sB1 = sm + 49152;

  const int t    = threadIdx.x;
  const int lane = t & 63;
  const int wave = t >> 6;

  int bid = (int)blockIdx.x;            // 640 = 32 m-tiles x 20 n-tiles, 640%8==0
  bid = (bid & 7) * 80 + (bid >> 3);    // XCD-contiguous chunks (bijective)
  const int m0 = (bid & 31) * 256;      // m-fastest: 32 blocks share one B panel
  const int n0 = (bid >> 5) * 256;

  const int fm = (wave >> 2) * 128;     // 0 / 128
  const int fn = (wave & 3) * 64;       // 0..192
  const int ml = lane & 15;
  const int lq = lane >> 4;

  // staging: half-tile = 128 rows x 64 cols f16 = 1024 16B-slots, 2 per thread.
  // slot s -> row r = s>>3, phys chunk pc = s&7, logical chunk lc = pc ^ (r&7).
  auto stageA = [&](f16* D, int half, int kt) {
    const int k0 = kt * 64;
    #pragma unroll
    for (int jj = 0; jj < 2; ++jj) {
      const int s  = jj * 512 + t;
      const int r  = s >> 3;
      const int lc = (s & 7) ^ (r & 7);
      int gr = m0 + half * 128 + r;
      gr = (gr < N_NODES) ? gr : (N_NODES - 1);   // clamp pad rows (stores guarded)
      const f16* g = A + (size_t)gr * F_IN + k0 + lc * 8;
      __builtin_amdgcn_global_load_lds((AS1 const void*)g,
                                       (AS3 void*)(D + half * 8192 + s * 8), 16, 0, 0);
    }
  };
  auto stageB = [&](f16* D, int half, int kt) {
    const int k0 = kt * 64;
    #pragma unroll
    for (int jj = 0; jj < 2; ++jj) {
      const int s  = jj * 512 + t;
      const int r  = s >> 3;
      const int lc = (s & 7) ^ (r & 7);
      const f16* g = BT + (size_t)(n0 + half * 128 + r) * F_IN + k0 + lc * 8;
      __builtin_amdgcn_global_load_lds((AS1 const void*)g,
                                       (AS3 void*)(D + half * 8192 + s * 8), 16, 0, 0);
    }
  };
  auto ldA = [&](const f16* S, int i, int kk) -> f16x8 {
    const int row = fm + i * 16 + ml;
    const int p   = (kk * 4 + lq) ^ (row & 7);
    return *(const f16x8*)(S + row * 64 + p * 8);
  };
  auto ldB = [&](const f16* S, int j, int kk) -> f16x8 {
    const int row = fn + j * 16 + ml;
    const int p   = (kk * 4 + lq) ^ (row & 7);
    return *(const f16x8*)(S + row * 64 + p * 8);
  };

  f32x4 acc[8][4] = {};
  f16x8 bf[4][2];

#define MMROW(i, A0_, A1_)                                                                   \
    _Pragma("unroll")                                                                        \
    for (int j = 0; j < 4; ++j) {                                                            \
      acc[i][j] = __builtin_amdgcn_mfma_f32_16x16x32_f16(A0_, bf[j][0], acc[i][j], 0, 0, 0); \
      acc[i][j] = __builtin_amdgcn_mfma_f32_16x16x32_f16(A1_, bf[j][1], acc[i][j], 0, 0, 0); \
    }

#define PHASE(SA, q, STG)                          \
  {                                                \
    const f16x8 p00 = ldA(SA, 2*(q),     0);       \
    const f16x8 p01 = ldA(SA, 2*(q),     1);       \
    const f16x8 p10 = ldA(SA, 2*(q) + 1, 0);       \
    const f16x8 p11 = ldA(SA, 2*(q) + 1, 1);       \
    STG;                                           \
    __builtin_amdgcn_s_barrier();                  \
    __builtin_amdgcn_sched_barrier(0);             \
    __builtin_amdgcn_s_setprio(1);                 \
    MMROW(2*(q),     p00, p01)                     \
    MMROW(2*(q) + 1, p10, p11)                     \
    __builtin_amdgcn_s_setprio(0);                 \
  }

#define ENDPH() { __builtin_amdgcn_s_barrier(); __builtin_amdgcn_sched_barrier(0); }
#define LOADB(SB) { _Pragma("unroll") for (int j = 0; j < 4; ++j) { bf[j][0] = ldB(SB, j, 0); bf[j][1] = ldB(SB, j, 1); } }

  // prologue: tile0 A+B, tile1 B; 12 loads, wait oldest 8 (tile0 complete)
  stageA(sA0, 0, 0); stageA(sA0, 1, 0);
  stageB(sB0, 0, 0); stageB(sB0, 1, 0);
  stageB(sB1, 0, 1); stageB(sB1, 1, 1);
  asm volatile("s_waitcnt vmcnt(4)" ::: "memory");
  __builtin_amdgcn_s_barrier();
  __builtin_amdgcn_sched_barrier(0);

  for (int it = 0; it < 20; ++it) {        // 40 K-tiles, 2 per iteration
    const int T  = 2 * it;
    const int t1 = T + 1;                              // <= 39 always
    const int t2 = (T + 2 < 40) ? T + 2 : 39;          // clamp: uniform load counts,
    const int t3 = (T + 3 < 40) ? T + 3 : 39;          // dup stages land in dead bufs

    // ---- K-tile T from buf0 ----
    LOADB(sB0)
    PHASE(sA0, 0, stageA(sA1, 0, t1)) ENDPH()
    PHASE(sA0, 1, stageA(sA1, 1, t1)) ENDPH()
    PHASE(sA0, 2, stageB(sB0, 0, t2)) ENDPH()
    PHASE(sA0, 3, stageB(sB0, 1, t2))
    asm volatile("s_waitcnt vmcnt(4)" ::: "memory");
    ENDPH()
    // ---- K-tile T+1 from buf1 ----
    LOADB(sB1)
    PHASE(sA1, 0, stageA(sA0, 0, t2)) ENDPH()
    PHASE(sA1, 1, stageA(sA0, 1, t2)) ENDPH()
    PHASE(sA1, 2, stageB(sB1, 0, t3)) ENDPH()
    PHASE(sA1, 3, stageB(sB1, 1, t3))
    asm volatile("s_waitcnt vmcnt(4)" ::: "memory");
    ENDPH()
  }

#undef MMROW
#undef PHASE
#undef ENDPH
#undef LOADB

  // epilogue: n0 block (256 wide) lies entirely in XL (n0<2560) or XR
  const bool left = (n0 < HC);
  f16* __restrict__ OUT = left ? XL : XR;
  const float* __restrict__ bias = left ? bl : br;
  const int nb = left ? n0 : (n0 - HC);
  const int rg = (lane >> 4) * 4;
  #pragma unroll
  for (int j = 0; j < 4; ++j) {
    const int gn = nb + fn + j * 16 + ml;
    const float bv = bias[gn];
    #pragma unroll
    for (int i = 0; i < 8; ++i) {
      #pragma unroll
      for (int r = 0; r < 4; ++r) {
        const int gm = m0 + fm + i * 16 + rg + r;
        if (gm < N_NODES) OUT[(size_t)gm * HC + gn] = (f16)(acc[i][j][r] + bv);
      }
    }
  }
}

// ---------------- CSR build ----------------
__global__ __launch_bounds__(256)
void count_edges(const int* __restrict__ dst, int* __restrict__ counts)
{
  const int e = blockIdx.x * 256 + threadIdx.x;
  if (e < N_EDGES) atomicAdd(&counts[dst[e]], 1);
}

__global__ __launch_bounds__(256)
void scan_offsets(const int* __restrict__ counts, int* __restrict__ offs, int* __restrict__ cur)
{
  __shared__ int wtot[4];
  const int t = threadIdx.x;
  const int lane = t & 63, wave = t >> 6;
  const int base = t * 32;
  int loc[32];
  int run = 0;
  #pragma unroll
  for (int i = 0; i < 32; ++i) {
    const int idx = base + i;
    const int v = (idx < N_NODES) ? counts[idx] : 0;
    loc[i] = run;
    run += v;
  }
  int incl = run;
  #pragma unroll
  for (int off = 1; off < 64; off <<= 1) {
    int y = __shfl_up(incl, off, 64);
    if (lane >= off) incl += y;
  }
  const int excl = incl - run;
  if (lane == 63) wtot[wave] = incl;
  __syncthreads();
  int wb = 0;
  for (int wv = 0; wv < wave; ++wv) wb += wtot[wv];
  const int mybase = wb + excl;
  #pragma unroll
  for (int i = 0; i < 32; ++i) {
    const int idx = base + i;
    if (idx < N_NODES) { offs[idx] = mybase + loc[i]; cur[idx] = mybase + loc[i]; }
  }
  if (t == 255) offs[N_NODES] = wb + incl;
}

__global__ __launch_bounds__(256)
void fill_csr(const int* __restrict__ dst, int* __restrict__ cur, int* __restrict__ eids)
{
  const int e = blockIdx.x * 256 + threadIdx.x;
  if (e < N_EDGES) {
    const int p = atomicAdd(&cur[dst[e]], 1);
    eids[p] = e;
  }
}

// ---- Fused edge phase: scores + online segment-softmax + aggregation, one pass ----
// Per half-wave = one head. Lane l32 owns channels {l32*8..l32*8+7} U {256+2*l32, +1}
// of its head (same set-union as before; reductions are order-independent), so the
// per-edge row gather is one 16B f16x8 + one 4B f16x2 instead of 10 scalar loads.
__global__ __launch_bounds__(256)
void gat_edge_fused(const f16* __restrict__ XL, const f16* __restrict__ XR,
                    const float* __restrict__ We, const float* __restrict__ att,
                    const float* __restrict__ eattr,
                    const int* __restrict__ src,
                    const int* __restrict__ offs, const int* __restrict__ eids,
                    const float* __restrict__ bias,
                    f16* __restrict__ out)
{
  const int n    = blockIdx.x;
  const int t    = threadIdx.x;
  const int wave = t >> 6;
  const int lane = t & 63;
  const int half = lane >> 5;
  const int l32  = lane & 31;
  const int h    = wave * 2 + half;
  const int c8   = h * CPH + l32 * 8;        // 8 contiguous channels (16B aligned)
  const int c2   = h * CPH + 256 + l32 * 2;  // 2 contiguous channels (4B aligned)

  float xr[10], wv[10], av[10];
  {
    const f16x8 v8 = *(const f16x8*)(XR + (size_t)n * HC + c8);
    const f16x2 v2 = *(const f16x2*)(XR + (size_t)n * HC + c2);
    #pragma unroll
    for (int k = 0; k < 8; ++k) xr[k] = (float)v8[k];
    xr[8] = (float)v2[0]; xr[9] = (float)v2[1];
  }
  {
    const float4 w0 = *(const float4*)(We + c8);
    const float4 w1 = *(const float4*)(We + c8 + 4);
    const float4 a0 = *(const float4*)(att + c8);
    const float4 a1 = *(const float4*)(att + c8 + 4);
    wv[0]=w0.x; wv[1]=w0.y; wv[2]=w0.z; wv[3]=w0.w;
    wv[4]=w1.x; wv[5]=w1.y; wv[6]=w1.z; wv[7]=w1.w;
    av[0]=a0.x; av[1]=a0.y; av[2]=a0.z; av[3]=a0.w;
    av[4]=a1.x; av[5]=a1.y; av[6]=a1.z; av[7]=a1.w;
    wv[8] = We[c2]; wv[9] = We[c2 + 1];
    av[8] = att[c2]; av[9] = att[c2 + 1];
  }

  float m = -3.0e38f, l = 0.f;
  float acc[10];
  #pragma unroll
  for (int k = 0; k < 10; ++k) acc[k] = 0.f;

  const int b = offs[n], e = offs[n + 1];
  for (int p = b; p < e; ++p) {
    const int eid  = eids[p];
    const int s    = src[eid];
    const float ea = eattr[eid];
    const f16* row = XL + (size_t)s * HC;
    const f16x8 v8 = *(const f16x8*)(row + c8);
    const f16x2 v2 = *(const f16x2*)(row + c2);
    float xl[10];
    #pragma unroll
    for (int k = 0; k < 8; ++k) xl[k] = (float)v8[k];
    xl[8] = (float)v2[0]; xl[9] = (float)v2[1];
    float partial = 0.f;
    #pragma unroll
    for (int k = 0; k < 10; ++k) {
      float v = xl[k] + xr[k] + ea * wv[k];
      v = (v > 0.f) ? v : SLOPE * v;
      partial += v * av[k];
    }
    #pragma unroll
    for (int msk = 16; msk >= 1; msk >>= 1)
      partial += __shfl_xor(partial, msk, 64);
    const float sc    = partial;
    const float mn    = fmaxf(m, sc);
    const float scale = __expf(m - mn);
    const float w     = __expf(sc - mn);
    l = l * scale + w;
    #pragma unroll
    for (int k = 0; k < 10; ++k) acc[k] = acc[k] * scale + w * xl[k];
    m = mn;
  }

  const float inv = (l > 0.f) ? 1.f / l : 0.f;   // deg-0 node -> out = bias (matches ref)
  f16x8 s8;
  #pragma unroll
  for (int k = 0; k < 8; ++k) s8[k] = (f16)(acc[k] * inv + bias[c8 + k]);
  f16x2 s2;
  s2[0] = (f16)(acc[8] * inv + bias[c2]);
  s2[1] = (f16)(acc[9] * inv + bias[c2 + 1]);
  *(f16x8*)(out + (size_t)n * HC + c8) = s8;
  *(f16x2*)(out + (size_t)n * HC + c2) = s2;
}

// ---------------- global mean pool (batch is sorted), f16 in, f32 out ----------------
__global__ __launch_bounds__(256)
void pool_kernel(const f16* __restrict__ Hm, const int* __restrict__ batch, float* __restrict__ out)
{
  __shared__ int se[2];
  const int g = blockIdx.x;
  const int chunk = blockIdx.y;
  const int t = threadIdx.x;
  if (t < 2) {
    const int target = g + t;
    int lo = 0, hi = N_NODES;
    while (lo < hi) { const int mid = (lo + hi) >> 1; if (batch[mid] < target) lo = mid + 1; else hi = mid; }
    se[t] = lo;
  }
  __syncthreads();
  const int s0 = se[0], s1 = se[1];
  const int c = chunk * 256 + t;
  float sum = 0.f;
  for (int n = s0; n < s1; ++n) sum += (float)Hm[(size_t)n * HC + c];
  int cnt = s1 - s0; if (cnt < 1) cnt = 1;
  out[g * HC + c] = sum / (float)cnt;
}

// ---------------- host: one GATv2 layer (A f16 -> OUT f16) ----------------
static void run_layer(const f16* A, const float* Wl, const float* bl,
                      const float* Wr, const float* br,
                      const float* We, const float* att, const float* bias,
                      const int* src, const float* eattr,
                      f16* WT, f16* XL, f16* XR,
                      const int* offs, const int* eids, f16* OUT, hipStream_t stream)
{
  dim3 tgrid(HC / 64, F_IN / 64);
  transpose_w<<<tgrid, 256, 0, stream>>>(Wl, WT);
  transpose_w<<<tgrid, 256, 0, stream>>>(Wr, WT + (size_t)HC * F_IN);
  gemm_fused<<<32 * (NW / 256), 512, 0, stream>>>(A, WT, bl, br, XL, XR);
  gat_edge_fused<<<N_NODES, 256, 0, stream>>>(XL, XR, We, att, eattr, src, offs, eids, bias, OUT);
}

extern "C" void kernel_launch(void* const* d_in, const int* in_sizes, int n_in,
                              void* d_out, int out_size, void* d_ws, size_t ws_size,
                              hipStream_t stream)
{
  const float* x     = (const float*)d_in[0];
  const int*   eidx  = (const int*)d_in[1];
  const float* eattr = (const float*)d_in[2];
  const int*   batch = (const int*)d_in[3];
  const float* Wl1  = (const float*)d_in[4];
  const float* bl1  = (const float*)d_in[5];
  const float* Wr1  = (const float*)d_in[6];
  const float* br1  = (const float*)d_in[7];
  const float* We1  = (const float*)d_in[8];
  const float* att1 = (const float*)d_in[9];
  const float* bias1= (const float*)d_in[10];
  const float* Wl2  = (const float*)d_in[11];
  const float* bl2  = (const float*)d_in[12];
  const float* Wr2  = (const float*)d_in[13];
  const float* br2  = (const float*)d_in[14];
  const float* We2  = (const float*)d_in[15];
  const float* att2 = (const float*)d_in[16];
  const float* bias2= (const float*)d_in[17];
  float* out = (float*)d_out;

  const int* src = eidx;
  const int* dst = eidx + N_EDGES;

  char* w = (char*)d_ws;
  auto take = [&](size_t b) { char* p = w; w += (b + 255) & ~(size_t)255; return p; };
  f16*   Xh    = (f16*)take((size_t)N_NODES * F_IN * 2);   // layer-1 A / layer-1 out (reused)
  f16*   H2h   = (f16*)take((size_t)N_NODES * HC * 2);     // layer-2 out
  f16*   WT    = (f16*)take((size_t)NW * F_IN * 2);        // fused transposed weights
  f16*   XL    = (f16*)take((size_t)N_NODES * HC * 2);
  f16*   XR    = (f16*)take((size_t)N_NODES * HC * 2);
  int*   counts= (int*)take((size_t)N_NODES * 4);
  int*   offs  = (int*)take((size_t)(N_NODES + 1) * 4);
  int*   cur   = (int*)take((size_t)N_NODES * 4);
  int*   eids  = (int*)take((size_t)N_EDGES * 4);

  hipMemsetAsync(counts, 0, N_NODES * 4, stream);
  count_edges<<<N_EDGES / 256, 256, 0, stream>>>(dst, counts);
  scan_offsets<<<1, 256, 0, stream>>>(counts, offs, cur);
  fill_csr<<<N_EDGES / 256, 256, 0, stream>>>(dst, cur, eids);

  cvt_f32_f16<<<(N_NODES * F_IN) / 1024, 256, 0, stream>>>(x, Xh, N_NODES * F_IN);

  // layer 1: Xh -> Xh (edge kernel writes after GEMM has consumed Xh; stream-ordered, safe)
  run_layer(Xh, Wl1, bl1, Wr1, br1, We1, att1, bias1, src, eattr,
            WT, XL, XR, offs, eids, Xh, stream);
  // layer 2: Xh -> H2h
  run_layer(Xh, Wl2, bl2, Wr2, br2, We2, att2, bias2, src, eattr,
            WT, XL, XR, offs, eids, H2h, stream);

  pool_kernel<<<dim3(NGRAPH, HC / 256), 256, 0, stream>>>(H2h, batch, out);
}

// Round 2
// 915.436 us; speedup vs baseline: 1.1470x; 1.1032x over previous
//
#include <hip/hip_runtime.h>

typedef unsigned short u16;
typedef _Float16 f16;
typedef _Float16 f16x8 __attribute__((ext_vector_type(8)));
typedef _Float16 f16x2 __attribute__((ext_vector_type(2)));
typedef float f32x4 __attribute__((ext_vector_type(4)));

#define AS1 __attribute__((address_space(1)))
#define AS3 __attribute__((address_space(3)))

constexpr int N_NODES = 8000;
constexpr int N_EDGES = 64000;
constexpr int F_IN    = 2560;   // in channels (== H*C, both layers)
constexpr int HEADS   = 8;
constexpr int CPH     = 320;    // channels per head
constexpr int HC      = 2560;   // HEADS*CPH
constexpr int NW      = 5120;   // fused GEMM output width (XL | XR)
constexpr int NGRAPH  = 16;
constexpr float SLOPE = 0.2f;

// ---------------- f32 -> f16 bulk convert (n divisible by 1024) ----------------
__global__ __launch_bounds__(256)
void cvt_f32_f16(const float* __restrict__ in, f16* __restrict__ out, int n)
{
  const int i = (blockIdx.x * 256 + threadIdx.x) * 4;
  if (i >= n) return;
  const float4 v = *(const float4*)(in + i);
  f16 o[4] = {(f16)v.x, (f16)v.y, (f16)v.z, (f16)v.w};
  *(ushort4*)(out + i) = *(const ushort4*)o;
}

// ------ weight transpose + convert: in f32 [R=2560][C=2560] -> out f16 [C][R] ------
__global__ __launch_bounds__(256)
void transpose_w(const float* __restrict__ in, f16* __restrict__ out)
{
  __shared__ u16 tile[64][66];     // +2 pad to break bank stride
  const int bx = blockIdx.x * 64;  // col tile (input)
  const int by = blockIdx.y * 64;  // row tile (input)
  const int tx = threadIdx.x & 63;
  const int ty = threadIdx.x >> 6;
  #pragma unroll
  for (int i = ty; i < 64; i += 4) {
    f16 h = (f16)in[(size_t)(by + i) * HC + bx + tx];
    u16 u; __builtin_memcpy(&u, &h, 2);
    tile[i][tx] = u;
  }
  __syncthreads();
  #pragma unroll
  for (int i = ty; i < 64; i += 4) {
    u16 u = tile[tx][i];
    f16 h; __builtin_memcpy(&h, &u, 2);
    out[(size_t)(bx + i) * F_IN + by + tx] = h;
  }
}

// ---- Fused GEMM: [XL|XR][M,5120](f16) = A[M,K](f16) @ BT[5120,K]^T + bias; fp32 acc ----
// 8-phase pipelined 256x256 tile, BK=64, 512 threads / 8 waves (2M x 4N),
// per-wave 128x64 output (8x4 16x16x32 fragments). 128 KiB LDS double buffer.
// Counted vmcnt(4) at phases 4/8 only; raw s_barrier; setprio around MFMA.
// Per-row XOR-8 16B-chunk swizzle on LDS (conflict-free, verified 0 conflicts).
//
// Grid->tile map (L2 locality): XCD k (= blockIdx%8) owns m-tiles 4k..4k+3, all
// 20 n-tiles; m-fastest within the chunk. Concurrent working set per XCD:
// 4 A panels (5.2 MB, ~L2-resident) + sliding B window (L3-served). Round 1's
// m-fastest-over-32 chunk put 42 MB of A panels per XCD -> FETCH 420 MB.
//
// Epilogue: vmcnt(0) drain, then per-wave LDS round-trip (swizzled) so global
// stores are full 128B lines (f16x8/lane) -- kills the 32B partial-line RMW
// that inflated WRITE_SIZE to 147 MB (ideal 82 MB).
__global__ __launch_bounds__(512, 2)
void gemm_fused(const f16* __restrict__ A, const f16* __restrict__ BT,
                const float* __restrict__ bl, const float* __restrict__ br,
                f16* __restrict__ XL, f16* __restrict__ XR)
{
  __shared__ __align__(16) f16 sm[65536];   // 128 KiB
  f16* const sA0 = sm;
  f16* const sA1 = sm + 16384;
  f16* const sB0 = sm + 32768;
  f16* const sB1 = sm + 49152;

  const int t    = threadIdx.x;
  const int lane = t & 63;
  const int wave = t >> 6;

  // XCD-local 2D chunk: xcd = bid%8 owns m-tiles [4*xcd, 4*xcd+3] x n 0..19
  const int bid0 = (int)blockIdx.x;      // 640 = 32 m-tiles x 20 n-tiles
  const int xcd  = bid0 & 7;
  const int ic   = bid0 >> 3;            // 0..79, dispatch order within XCD
  const int m0   = (xcd * 4 + (ic & 3)) * 256;   // m-fastest: A panels L2-pinned
  const int n0   = (ic >> 2) * 256;

  const int fm = (wave >> 2) * 128;     // 0 / 128
  const int fn = (wave & 3) * 64;       // 0..192
  const int ml = lane & 15;
  const int lq = lane >> 4;

  auto stageA = [&](f16* D, int half, int kt) {
    const int k0 = kt * 64;
    #pragma unroll
    for (int jj = 0; jj < 2; ++jj) {
      const int s  = jj * 512 + t;
      const int r  = s >> 3;
      const int lc = (s & 7) ^ (r & 7);
      int gr = m0 + half * 128 + r;
      gr = (gr < N_NODES) ? gr : (N_NODES - 1);   // clamp pad rows (stores guarded)
      const f16* g = A + (size_t)gr * F_IN + k0 + lc * 8;
      __builtin_amdgcn_global_load_lds((AS1 const void*)g,
                                       (AS3 void*)(D + half * 8192 + s * 8), 16, 0, 0);
    }
  };
  auto stageB = [&](f16* D, int half, int kt) {
    const int k0 = kt * 64;
    #pragma unroll
    for (int jj = 0; jj < 2; ++jj) {
      const int s  = jj * 512 + t;
      const int r  = s >> 3;
      const int lc = (s & 7) ^ (r & 7);
      const f16* g = BT + (size_t)(n0 + half * 128 + r) * F_IN + k0 + lc * 8;
      __builtin_amdgcn_global_load_lds((AS1 const void*)g,
                                       (AS3 void*)(D + half * 8192 + s * 8), 16, 0, 0);
    }
  };
  auto ldA = [&](const f16* S, int i, int kk) -> f16x8 {
    const int row = fm + i * 16 + ml;
    const int p   = (kk * 4 + lq) ^ (row & 7);
    return *(const f16x8*)(S + row * 64 + p * 8);
  };
  auto ldB = [&](const f16* S, int j, int kk) -> f16x8 {
    const int row = fn + j * 16 + ml;
    const int p   = (kk * 4 + lq) ^ (row & 7);
    return *(const f16x8*)(S + row * 64 + p * 8);
  };

  f32x4 acc[8][4] = {};
  f16x8 bf[4][2];

#define MMROW(i, A0_, A1_)                                                                   \
    _Pragma("unroll")                                                                        \
    for (int j = 0; j < 4; ++j) {                                                            \
      acc[i][j] = __builtin_amdgcn_mfma_f32_16x16x32_f16(A0_, bf[j][0], acc[i][j], 0, 0, 0); \
      acc[i][j] = __builtin_amdgcn_mfma_f32_16x16x32_f16(A1_, bf[j][1], acc[i][j], 0, 0, 0); \
    }

#define PHASE(SA, q, STG)                          \
  {                                                \
    const f16x8 p00 = ldA(SA, 2*(q),     0);       \
    const f16x8 p01 = ldA(SA, 2*(q),     1);       \
    const f16x8 p10 = ldA(SA, 2*(q) + 1, 0);       \
    const f16x8 p11 = ldA(SA, 2*(q) + 1, 1);       \
    STG;                                           \
    __builtin_amdgcn_s_barrier();                  \
    __builtin_amdgcn_sched_barrier(0);             \
    __builtin_amdgcn_s_setprio(1);                 \
    MMROW(2*(q),     p00, p01)                     \
    MMROW(2*(q) + 1, p10, p11)                     \
    __builtin_amdgcn_s_setprio(0);                 \
  }

#define ENDPH() { __builtin_amdgcn_s_barrier(); __builtin_amdgcn_sched_barrier(0); }
#define LOADB(SB) { _Pragma("unroll") for (int j = 0; j < 4; ++j) { bf[j][0] = ldB(SB, j, 0); bf[j][1] = ldB(SB, j, 1); } }

  // prologue: tile0 A+B, tile1 B; 12 loads, wait oldest 8 (tile0 complete)
  stageA(sA0, 0, 0); stageA(sA0, 1, 0);
  stageB(sB0, 0, 0); stageB(sB0, 1, 0);
  stageB(sB1, 0, 1); stageB(sB1, 1, 1);
  asm volatile("s_waitcnt vmcnt(4)" ::: "memory");
  __builtin_amdgcn_s_barrier();
  __builtin_amdgcn_sched_barrier(0);

  for (int it = 0; it < 20; ++it) {        // 40 K-tiles, 2 per iteration
    const int T  = 2 * it;
    const int t1 = T + 1;                              // <= 39 always
    const int t2 = (T + 2 < 40) ? T + 2 : 39;          // clamp: uniform load counts,
    const int t3 = (T + 3 < 40) ? T + 3 : 39;          // dup stages land in dead bufs

    // ---- K-tile T from buf0 ----
    LOADB(sB0)
    PHASE(sA0, 0, stageA(sA1, 0, t1)) ENDPH()
    PHASE(sA0, 1, stageA(sA1, 1, t1)) ENDPH()
    PHASE(sA0, 2, stageB(sB0, 0, t2)) ENDPH()
    PHASE(sA0, 3, stageB(sB0, 1, t2))
    asm volatile("s_waitcnt vmcnt(4)" ::: "memory");
    ENDPH()
    // ---- K-tile T+1 from buf1 ----
    LOADB(sB1)
    PHASE(sA1, 0, stageA(sA0, 0, t2)) ENDPH()
    PHASE(sA1, 1, stageA(sA0, 1, t2)) ENDPH()
    PHASE(sA1, 2, stageB(sB1, 0, t3)) ENDPH()
    PHASE(sA1, 3, stageB(sB1, 1, t3))
    asm volatile("s_waitcnt vmcnt(4)" ::: "memory");
    ENDPH()
  }

#undef MMROW
#undef PHASE
#undef ENDPH
#undef LOADB

  // ---- epilogue: drain pending stages, then LDS round-trip for coalesced stores ----
  asm volatile("s_waitcnt vmcnt(0)" ::: "memory");
  __builtin_amdgcn_s_barrier();

  const bool left = (n0 < HC);
  f16* __restrict__ OUT = left ? XL : XR;
  const float* __restrict__ bias = left ? bl : br;
  const int nb = left ? n0 : (n0 - HC);
  const int rg = (lane >> 4) * 4;
  f16* const wbase = sm + wave * 8192;   // 16 KB per wave (128 rows x 64 cols)

  #pragma unroll
  for (int j = 0; j < 4; ++j) {
    const float bv = bias[nb + fn + j * 16 + ml];
    #pragma unroll
    for (int i = 0; i < 8; ++i) {
      #pragma unroll
      for (int r = 0; r < 4; ++r) {
        const int row = i * 16 + rg + r;
        const int col = j * 16 + ml;
        const int pc  = (col >> 3) ^ (row & 7);
        wbase[row * 64 + pc * 8 + (col & 7)] = (f16)(acc[i][j][r] + bv);
      }
    }
  }
  __syncthreads();
  #pragma unroll
  for (int it = 0; it < 16; ++it) {
    const int row = it * 8 + (lane >> 3);
    const int ch  = lane & 7;
    const int pc  = ch ^ (row & 7);
    const f16x8 v = *(const f16x8*)(wbase + row * 64 + pc * 8);
    const int gm = m0 + fm + row;
    if (gm < N_NODES)
      *(f16x8*)(OUT + (size_t)gm * HC + nb + fn + ch * 8) = v;
  }
}

// ---------------- CSR build ----------------
__global__ __launch_bounds__(256)
void count_edges(const int* __restrict__ dst, int* __restrict__ counts)
{
  const int e = blockIdx.x * 256 + threadIdx.x;
  if (e < N_EDGES) atomicAdd(&counts[dst[e]], 1);
}

__global__ __launch_bounds__(256)
void scan_offsets(const int* __restrict__ counts, int* __restrict__ offs, int* __restrict__ cur)
{
  __shared__ int wtot[4];
  const int t = threadIdx.x;
  const int lane = t & 63, wave = t >> 6;
  const int base = t * 32;
  int loc[32];
  int run = 0;
  #pragma unroll
  for (int i = 0; i < 32; ++i) {
    const int idx = base + i;
    const int v = (idx < N_NODES) ? counts[idx] : 0;
    loc[i] = run;
    run += v;
  }
  int incl = run;
  #pragma unroll
  for (int off = 1; off < 64; off <<= 1) {
    int y = __shfl_up(incl, off, 64);
    if (lane >= off) incl += y;
  }
  const int excl = incl - run;
  if (lane == 63) wtot[wave] = incl;
  __syncthreads();
  int wb = 0;
  for (int wv = 0; wv < wave; ++wv) wb += wtot[wv];
  const int mybase = wb + excl;
  #pragma unroll
  for (int i = 0; i < 32; ++i) {
    const int idx = base + i;
    if (idx < N_NODES) { offs[idx] = mybase + loc[i]; cur[idx] = mybase + loc[i]; }
  }
  if (t == 255) offs[N_NODES] = wb + incl;
}

__global__ __launch_bounds__(256)
void fill_csr(const int* __restrict__ dst, int* __restrict__ cur, int* __restrict__ eids)
{
  const int e = blockIdx.x * 256 + threadIdx.x;
  if (e < N_EDGES) {
    const int p = atomicAdd(&cur[dst[e]], 1);
    eids[p] = e;
  }
}

// ---- Fused edge phase: scores + online segment-softmax + aggregation, one pass ----
// Per half-wave = one head. Lane l32 owns channels {l32*8..+7} U {256+2*l32,+1}.
// Software-pipelined edge loop (branch-free): while edge p computes, the XL row
// of p+1 and the eid/src/eattr of p+2 are in flight -- breaks the serial
// eids->src->row pointer-chase (~700cy L2/L3) that dominated this kernel.
__global__ __launch_bounds__(256)
void gat_edge_fused(const f16* __restrict__ XL, const f16* __restrict__ XR,
                    const float* __restrict__ We, const float* __restrict__ att,
                    const float* __restrict__ eattr,
                    const int* __restrict__ src,
                    const int* __restrict__ offs, const int* __restrict__ eids,
                    const float* __restrict__ bias,
                    f16* __restrict__ out)
{
  const int n    = blockIdx.x;
  const int t    = threadIdx.x;
  const int wave = t >> 6;
  const int lane = t & 63;
  const int half = lane >> 5;
  const int l32  = lane & 31;
  const int h    = wave * 2 + half;
  const int c8   = h * CPH + l32 * 8;        // 8 contiguous channels (16B aligned)
  const int c2   = h * CPH + 256 + l32 * 2;  // 2 contiguous channels (4B aligned)

  float xr[10], wv[10], av[10];
  {
    const f16x8 v8 = *(const f16x8*)(XR + (size_t)n * HC + c8);
    const f16x2 v2 = *(const f16x2*)(XR + (size_t)n * HC + c2);
    #pragma unroll
    for (int k = 0; k < 8; ++k) xr[k] = (float)v8[k];
    xr[8] = (float)v2[0]; xr[9] = (float)v2[1];
  }
  {
    const float4 w0 = *(const float4*)(We + c8);
    const float4 w1 = *(const float4*)(We + c8 + 4);
    const float4 a0 = *(const float4*)(att + c8);
    const float4 a1 = *(const float4*)(att + c8 + 4);
    wv[0]=w0.x; wv[1]=w0.y; wv[2]=w0.z; wv[3]=w0.w;
    wv[4]=w1.x; wv[5]=w1.y; wv[6]=w1.z; wv[7]=w1.w;
    av[0]=a0.x; av[1]=a0.y; av[2]=a0.z; av[3]=a0.w;
    av[4]=a1.x; av[5]=a1.y; av[6]=a1.z; av[7]=a1.w;
    wv[8] = We[c2]; wv[9] = We[c2 + 1];
    av[8] = att[c2]; av[9] = att[c2 + 1];
  }

  float m = -3.0e38f, l = 0.f;
  float acc[10];
  #pragma unroll
  for (int k = 0; k < 10; ++k) acc[k] = 0.f;

  const int b = offs[n], e = offs[n + 1];
  if (b < e) {
    // prologue: meta+row for edge b, meta for edge b+1
    int eidA = eids[b];
    int sA   = src[eidA];
    float eaA = eattr[eidA];
    f16x8 v8A = *(const f16x8*)(XL + (size_t)sA * HC + c8);
    f16x2 v2A = *(const f16x2*)(XL + (size_t)sA * HC + c2);
    int sB; float eaB;
    if (b + 1 < e) { const int eid = eids[b + 1]; sB = src[eid]; eaB = eattr[eid]; }
    else           { sB = sA; eaB = 0.f; }

    for (int p = b; p < e; ++p) {
      // prefetch row of p+1 (sB valid even past end -> harmless load)
      const f16* rowN = XL + (size_t)sB * HC;
      const f16x8 v8N = *(const f16x8*)(rowN + c8);
      const f16x2 v2N = *(const f16x2*)(rowN + c2);
      // prefetch meta of p+2 (clamped -> branch-free)
      const int pn   = (p + 2 < e) ? (p + 2) : (e - 1);
      const int eidN = eids[pn];
      const int sC   = src[eidN];
      const float eaC = eattr[eidN];

      // process edge p
      float xl[10];
      #pragma unroll
      for (int k = 0; k < 8; ++k) xl[k] = (float)v8A[k];
      xl[8] = (float)v2A[0]; xl[9] = (float)v2A[1];
      float partial = 0.f;
      #pragma unroll
      for (int k = 0; k < 10; ++k) {
        float v = xl[k] + xr[k] + eaA * wv[k];
        v = (v > 0.f) ? v : SLOPE * v;
        partial += v * av[k];
      }
      #pragma unroll
      for (int msk = 16; msk >= 1; msk >>= 1)
        partial += __shfl_xor(partial, msk, 64);
      const float sc    = partial;
      const float mn    = fmaxf(m, sc);
      const float scale = __expf(m - mn);
      const float w     = __expf(sc - mn);
      l = l * scale + w;
      #pragma unroll
      for (int k = 0; k < 10; ++k) acc[k] = acc[k] * scale + w * xl[k];
      m = mn;

      // shift pipeline
      v8A = v8N; v2A = v2N; eaA = eaB;
      sB = sC; eaB = eaC;
    }
  }

  const float inv = (l > 0.f) ? 1.f / l : 0.f;   // deg-0 node -> out = bias (matches ref)
  f16x8 s8;
  #pragma unroll
  for (int k = 0; k < 8; ++k) s8[k] = (f16)(acc[k] * inv + bias[c8 + k]);
  f16x2 s2;
  s2[0] = (f16)(acc[8] * inv + bias[c2]);
  s2[1] = (f16)(acc[9] * inv + bias[c2 + 1]);
  *(f16x8*)(out + (size_t)n * HC + c8) = s8;
  *(f16x2*)(out + (size_t)n * HC + c2) = s2;
}

// ---------------- global mean pool (batch is sorted), f16 in, f32 out ----------------
__global__ __launch_bounds__(256)
void pool_kernel(const f16* __restrict__ Hm, const int* __restrict__ batch, float* __restrict__ out)
{
  __shared__ int se[2];
  const int g = blockIdx.x;
  const int chunk = blockIdx.y;
  const int t = threadIdx.x;
  if (t < 2) {
    const int target = g + t;
    int lo = 0, hi = N_NODES;
    while (lo < hi) { const int mid = (lo + hi) >> 1; if (batch[mid] < target) lo = mid + 1; else hi = mid; }
    se[t] = lo;
  }
  __syncthreads();
  const int s0 = se[0], s1 = se[1];
  const int c = chunk * 256 + t;
  float sum = 0.f;
  for (int n = s0; n < s1; ++n) sum += (float)Hm[(size_t)n * HC + c];
  int cnt = s1 - s0; if (cnt < 1) cnt = 1;
  out[g * HC + c] = sum / (float)cnt;
}

// ---------------- host: one GATv2 layer (A f16 -> OUT f16) ----------------
static void run_layer(const f16* A, const float* Wl, const float* bl,
                      const float* Wr, const float* br,
                      const float* We, const float* att, const float* bias,
                      const int* src, const float* eattr,
                      f16* WT, f16* XL, f16* XR,
                      const int* offs, const int* eids, f16* OUT, hipStream_t stream)
{
  dim3 tgrid(HC / 64, F_IN / 64);
  transpose_w<<<tgrid, 256, 0, stream>>>(Wl, WT);
  transpose_w<<<tgrid, 256, 0, stream>>>(Wr, WT + (size_t)HC * F_IN);
  gemm_fused<<<32 * (NW / 256), 512, 0, stream>>>(A, WT, bl, br, XL, XR);
  gat_edge_fused<<<N_NODES, 256, 0, stream>>>(XL, XR, We, att, eattr, src, offs, eids, bias, OUT);
}

extern "C" void kernel_launch(void* const* d_in, const int* in_sizes, int n_in,
                              void* d_out, int out_size, void* d_ws, size_t ws_size,
                              hipStream_t stream)
{
  const float* x     = (const float*)d_in[0];
  const int*   eidx  = (const int*)d_in[1];
  const float* eattr = (const float*)d_in[2];
  const int*   batch = (const int*)d_in[3];
  const float* Wl1  = (const float*)d_in[4];
  const float* bl1  = (const float*)d_in[5];
  const float* Wr1  = (const float*)d_in[6];
  const float* br1  = (const float*)d_in[7];
  const float* We1  = (const float*)d_in[8];
  const float* att1 = (const float*)d_in[9];
  const float* bias1= (const float*)d_in[10];
  const float* Wl2  = (const float*)d_in[11];
  const float* bl2  = (const float*)d_in[12];
  const float* Wr2  = (const float*)d_in[13];
  const float* br2  = (const float*)d_in[14];
  const float* We2  = (const float*)d_in[15];
  const float* att2 = (const float*)d_in[16];
  const float* bias2= (const float*)d_in[17];
  float* out = (float*)d_out;

  const int* src = eidx;
  const int* dst = eidx + N_EDGES;

  char* w = (char*)d_ws;
  auto take = [&](size_t b) { char* p = w; w += (b + 255) & ~(size_t)255; return p; };
  f16*   Xh    = (f16*)take((size_t)N_NODES * F_IN * 2);   // layer-1 A / layer-1 out (reused)
  f16*   H2h   = (f16*)take((size_t)N_NODES * HC * 2);     // layer-2 out
  f16*   WT    = (f16*)take((size_t)NW * F_IN * 2);        // fused transposed weights
  f16*   XL    = (f16*)take((size_t)N_NODES * HC * 2);
  f16*   XR    = (f16*)take((size_t)N_NODES * HC * 2);
  int*   counts= (int*)take((size_t)N_NODES * 4);
  int*   offs  = (int*)take((size_t)(N_NODES + 1) * 4);
  int*   cur   = (int*)take((size_t)N_NODES * 4);
  int*   eids  = (int*)take((size_t)N_EDGES * 4);

  hipMemsetAsync(counts, 0, N_NODES * 4, stream);
  count_edges<<<N_EDGES / 256, 256, 0, stream>>>(dst, counts);
  scan_offsets<<<1, 256, 0, stream>>>(counts, offs, cur);
  fill_csr<<<N_EDGES / 256, 256, 0, stream>>>(dst, cur, eids);

  cvt_f32_f16<<<(N_NODES * F_IN) / 1024, 256, 0, stream>>>(x, Xh, N_NODES * F_IN);

  // layer 1: Xh -> Xh (edge kernel writes after GEMM has consumed Xh; stream-ordered, safe)
  run_layer(Xh, Wl1, bl1, Wr1, br1, We1, att1, bias1, src, eattr,
            WT, XL, XR, offs, eids, Xh, stream);
  // layer 2: Xh -> H2h
  run_layer(Xh, Wl2, bl2, Wr2, br2, We2, att2, bias2, src, eattr,
            WT, XL, XR, offs, eids, H2h, stream);

  pool_kernel<<<dim3(NGRAPH, HC / 256), 256, 0, stream>>>(H2h, batch, out);
}